// Round 1
// baseline (1258.604 us; speedup 1.0000x reference)
//
#include <hip/hip_runtime.h>

// ---------------------------------------------------------------------------
// GNNQNetwork: hetero-GAT (6 edge types) + pooling + MLP head, MI355X fp32.
//
// Algebraic collapse: hs = x_src @ C_et + cb_et where C_et = encW_S @ W_et
// (K_in x 128, K_in in {8,13,4}); ls/ld are K_in-dim dots. No [N,128]
// intermediate is ever materialized.
// ---------------------------------------------------------------------------

constexpr int kNT   = 100000;
constexpr int kNRV  = 200000;
constexpr int kNR   = 300000;
constexpr int kE    = 400000;
constexpr int kTOTD = 1200000;   // 2*(NT+NRV+NR), concatenated dst-count array
constexpr int kTOTE = 2400000;   // 6*E
constexpr int kNB1  = 1172;      // ceil(kTOTD/1024)

// workspace offsets, in 4-byte units
constexpr long long OFF_CC   = 0;        // [1200000] int  counts
constexpr long long OFF_CU   = 1200000;  // [1200000] int  cursors
constexpr long long OFF_RS   = 2400000;  // [1200001] int  row starts (global scan)
constexpr long long OFF_SE   = 3600004;  // [2400000] int  sorted edge ids
constexpr long long OFF_BSUM = 6000004;  // [1172]
constexpr long long OFF_BOFF = 6001184;  // [1280]
constexpr long long OFF_C    = 6002464;  // [6*2176] float: C rows + cb at 2048
constexpr long long OFF_VS   = 6015520;  // [6*20] float: vs vec + ofs at [16]
constexpr long long OFF_VD   = 6015640;  // [6*20]
constexpr long long OFF_LS   = 6015760;  // [1200000] float src logits
constexpr long long OFF_LD   = 7215760;  // [1200000] float dst logits
constexpr long long OFF_XCAT = 8415760;  // [64*512] float pooled+player
// total ~ 33.8 MB

// ---------------------------------------------------------------------------
__global__ __launch_bounds__(256) void zero_kernel(int* cc, float* xcat, int* rs) {
  int i = blockIdx.x * 256 + threadIdx.x;
  if (i < kTOTE) cc[i] = 0;                  // zeroes CC and CU (contiguous)
  if (i < 64 * 512) xcat[i] = 0.f;
  if (i == 0) rs[kTOTD] = kTOTE;             // scan sentinel
}

// ---------------------------------------------------------------------------
__global__ __launch_bounds__(256) void precompute_kernel(
    const float* encW_t, const float* encb_t,
    const float* encW_rv, const float* encb_rv,
    const float* encW_r, const float* encb_r,
    const float* W0, const float* as0, const float* ad0,
    const float* W1, const float* as1, const float* ad1,
    const float* W2, const float* as2, const float* ad2,
    const float* W3, const float* as3, const float* ad3,
    const float* W4, const float* as4, const float* ad4,
    const float* W5, const float* as5, const float* ad5,
    float* Cws, float* vsw, float* vdw)
{
  const float* encW[3] = {encW_t, encW_rv, encW_r};
  const float* encb[3] = {encb_t, encb_rv, encb_r};
  const int    Ks[3]   = {8, 13, 4};
  const float* Wv[6]  = {W0, W1, W2, W3, W4, W5};
  const float* asv[6] = {as0, as1, as2, as3, as4, as5};
  const float* adv[6] = {ad0, ad1, ad2, ad3, ad4, ad5};
  const int srcT[6] = {1, 0, 2, 1, 0, 2};   // et -> src node type {t=0,rv=1,r=2}
  const int dstT[6] = {0, 1, 1, 2, 2, 0};

  __shared__ float Cl[2176];
  __shared__ float wv[128];

  int et = blockIdx.x;
  int tid = threadIdx.x;
  int st = srcT[et], dt = dstT[et];
  const float* eW = encW[st];
  const float* eB = encb[st];
  int K = Ks[st];
  const float* W = Wv[et];
  const float* a_s = asv[et];
  const float* a_d = adv[et];
  float* Cslot = Cws + et * 2176;

  // C[k][j] = sum_m encW_S[k][m] * W[m][j];  cb[j] = sum_m encb_S[m]*W[m][j]
  for (int idx = tid; idx < (K + 1) * 128; idx += 256) {
    int r = idx >> 7, j = idx & 127;
    const float* row = (r < K) ? (eW + r * 128) : eB;
    float acc = 0.f;
    for (int m = 0; m < 128; ++m) acc += row[m] * W[m * 128 + j];
    int o = (r < K) ? (r * 128 + j) : (2048 + j);
    Cl[o] = acc;
    Cslot[o] = acc;
  }
  // wv[m] = sum_j W[m][j] * a_d[j]
  if (tid < 128) {
    float acc = 0.f;
    for (int j = 0; j < 128; ++j) acc += W[tid * 128 + j] * a_d[j];
    wv[tid] = acc;
  }
  __syncthreads();
  // vs[k] = C row k . a_s ; ofs_s = cb . a_s
  if (tid <= K) {
    const float* row = (tid < K) ? (Cl + tid * 128) : (Cl + 2048);
    float acc = 0.f;
    for (int j = 0; j < 128; ++j) acc += row[j] * a_s[j];
    vsw[et * 20 + (tid < K ? tid : 16)] = acc;
  }
  // vd[k] = encW_D row k . wv ; ofs_d = encb_D . wv
  int KD = Ks[dt];
  if (tid >= 32 && tid <= 32 + KD) {
    int k = tid - 32;
    const float* row = (k < KD) ? (encW[dt] + k * 128) : encb[dt];
    float acc = 0.f;
    for (int m = 0; m < 128; ++m) acc += row[m] * wv[m];
    vdw[et * 20 + (k < KD ? k : 16)] = acc;
  }
}

// ---------------------------------------------------------------------------
template <int K>
__global__ __launch_bounds__(256) void logit_kernel(
    const float* __restrict__ x, int N,
    const float* __restrict__ vsA, const float* __restrict__ vsB,
    const float* __restrict__ vdA, const float* __restrict__ vdB,
    float* __restrict__ lsA, float* __restrict__ lsB,
    float* __restrict__ ldA, float* __restrict__ ldB)
{
  int n = blockIdx.x * 256 + threadIdx.x;
  if (n >= N) return;
  const float* xr = x + (long long)n * K;
  float a0 = 0.f, a1 = 0.f, a2 = 0.f, a3 = 0.f;
#pragma unroll
  for (int k = 0; k < K; ++k) {
    float xv = xr[k];
    a0 += xv * vsA[k]; a1 += xv * vsB[k];
    a2 += xv * vdA[k]; a3 += xv * vdB[k];
  }
  lsA[n] = a0 + vsA[16]; lsB[n] = a1 + vsB[16];
  ldA[n] = a2 + vdA[16]; ldB[n] = a3 + vdB[16];
}

// ---------------------------------------------------------------------------
__global__ __launch_bounds__(256) void hist_kernel(
    const int* d0, const int* d1, const int* d2,
    const int* d3, const int* d4, const int* d5, int* CC)
{
  int i = blockIdx.x * 256 + threadIdx.x;
  if (i >= kTOTE) return;
  int et = i / kE;
  int e = i - et * kE;
  const int* dp; int sb;
  switch (et) {
    case 0: dp = d0; sb = 0;       break;
    case 1: dp = d1; sb = 100000;  break;
    case 2: dp = d2; sb = 300000;  break;
    case 3: dp = d3; sb = 500000;  break;
    case 4: dp = d4; sb = 800000;  break;
    default: dp = d5; sb = 1100000; break;
  }
  atomicAdd(&CC[sb + dp[e]], 1);
}

// ---------------------------------------------------------------------------
__global__ __launch_bounds__(256) void scan1_kernel(const int* __restrict__ CC, int* bsum) {
  __shared__ int sd[256];
  int b = blockIdx.x, t = threadIdx.x;
  int i0 = b * 1024 + t * 4;
  int s = 0;
  if (i0 + 3 < kTOTD) {
    int4 v = *(const int4*)(CC + i0);
    s = v.x + v.y + v.z + v.w;
  } else {
    for (int j = 0; j < 4; ++j) if (i0 + j < kTOTD) s += CC[i0 + j];
  }
  sd[t] = s; __syncthreads();
  for (int o = 128; o > 0; o >>= 1) { if (t < o) sd[t] += sd[t + o]; __syncthreads(); }
  if (t == 0) bsum[b] = sd[0];
}

__global__ __launch_bounds__(256) void scan2_kernel(const int* __restrict__ bsum, int* boff) {
  __shared__ int sc[256];
  int t = threadIdx.x;
  int g[5], c[5], run = 0;
  for (int j = 0; j < 5; ++j) {
    int idx = t * 5 + j;
    g[j] = (idx < kNB1) ? bsum[idx] : 0;
    run += g[j]; c[j] = run;
  }
  sc[t] = run; __syncthreads();
  for (int o = 1; o < 256; o <<= 1) {
    int v = (t >= o) ? sc[t - o] : 0;
    __syncthreads();
    sc[t] += v;
    __syncthreads();
  }
  int ex = sc[t] - run;
  for (int j = 0; j < 5; ++j) {
    int idx = t * 5 + j;
    if (idx < kNB1) boff[idx] = ex + c[j] - g[j];
  }
}

__global__ __launch_bounds__(256) void scan3_kernel(const int* __restrict__ CC,
                                                    const int* __restrict__ boff,
                                                    int* __restrict__ RS) {
  __shared__ int sc[256];
  int b = blockIdx.x, t = threadIdx.x;
  int i0 = b * 1024 + t * 4;
  int v[4];
  if (i0 + 3 < kTOTD) {
    int4 q = *(const int4*)(CC + i0);
    v[0] = q.x; v[1] = q.y; v[2] = q.z; v[3] = q.w;
  } else {
    for (int j = 0; j < 4; ++j) v[j] = (i0 + j < kTOTD) ? CC[i0 + j] : 0;
  }
  int run = 0, inc[4];
  for (int j = 0; j < 4; ++j) { run += v[j]; inc[j] = run; }
  sc[t] = run; __syncthreads();
  for (int o = 1; o < 256; o <<= 1) {
    int x = (t >= o) ? sc[t - o] : 0;
    __syncthreads();
    sc[t] += x;
    __syncthreads();
  }
  int ex = boff[b] + sc[t] - run;
  for (int j = 0; j < 4; ++j)
    if (i0 + j < kTOTD) RS[i0 + j] = ex + inc[j] - v[j];
}

// ---------------------------------------------------------------------------
__global__ __launch_bounds__(256) void scatter_kernel(
    const int* d0, const int* d1, const int* d2,
    const int* d3, const int* d4, const int* d5,
    const int* __restrict__ RS, int* CU, int* SE)
{
  int i = blockIdx.x * 256 + threadIdx.x;
  if (i >= kTOTE) return;
  int et = i / kE;
  int e = i - et * kE;
  const int* dp; int sb;
  switch (et) {
    case 0: dp = d0; sb = 0;       break;
    case 1: dp = d1; sb = 100000;  break;
    case 2: dp = d2; sb = 300000;  break;
    case 3: dp = d3; sb = 500000;  break;
    case 4: dp = d4; sb = 800000;  break;
    default: dp = d5; sb = 1100000; break;
  }
  int d = dp[e];
  int p = RS[sb + d] + atomicAdd(&CU[sb + d], 1);
  SE[p] = e;
}

// ---------------------------------------------------------------------------
template <int K>
__device__ __forceinline__ void agg_list(
    const int* __restrict__ RS, const int* __restrict__ SE, int base,
    const int* __restrict__ src, const float* __restrict__ x,
    const float* __restrict__ CL, const float* __restrict__ ls, float ldn,
    int lane, float& p0, float& p1)
{
  int s0 = RS[base], s1 = RS[base + 1];
  if (s0 >= s1) return;
  // denominator (softmax without max-shift: alpha invariant, logits O(10))
  float denom = 0.f;
  for (int c = s0; c < s1; c += 64) {
    int idx = c + lane;
    float w = 0.f;
    if (idx < s1) {
      int e = SE[idx];
      int s = src[e];
      float t = ls[s] + ldn;
      t = t > 0.f ? t : 0.2f * t;
      w = __expf(t);
    }
#pragma unroll
    for (int m = 32; m >= 1; m >>= 1) w += __shfl_xor(w, m, 64);
    denom += w;
  }
  float inv = 1.f / fmaxf(denom, 1e-16f);
  // messages
  for (int c = s0; c < s1; c += 64) {
    int idx = c + lane;
    int sR = 0; float wR = 0.f;
    if (idx < s1) {
      int e = SE[idx];
      sR = src[e];
      float t = ls[sR] + ldn;
      t = t > 0.f ? t : 0.2f * t;
      wR = __expf(t);
    }
    int cc = min(64, s1 - c);
    for (int j = 0; j < cc; ++j) {
      int s = __shfl(sR, j, 64);
      float alpha = __shfl(wR, j, 64) * inv;
      const float* xr = x + (long long)s * K;
      float m0 = CL[2048 + lane], m1 = CL[2048 + 64 + lane];  // cb
#pragma unroll
      for (int k = 0; k < K; ++k) {
        float xv = xr[k];
        m0 += xv * CL[k * 128 + lane];
        m1 += xv * CL[k * 128 + 64 + lane];
      }
      p0 += alpha * m0;
      p1 += alpha * m1;
    }
  }
}

template <int KA, int KB>
__global__ __launch_bounds__(256) void agg_kernel(
    const int* __restrict__ RS, const int* __restrict__ SE,
    int sbA, const int* __restrict__ srcA, const float* __restrict__ xA,
    const float* __restrict__ CA, const float* __restrict__ lsA, const float* __restrict__ ldA,
    int sbB, const int* __restrict__ srcB, const float* __restrict__ xB,
    const float* __restrict__ CB, const float* __restrict__ lsB, const float* __restrict__ ldB,
    const int* __restrict__ batch, float* __restrict__ xcat, int colofs, int Nd)
{
  __shared__ float CLa[2176];
  __shared__ float CLb[2176];
  int tid = threadIdx.x;
  for (int i = tid; i < 2176; i += 256) { CLa[i] = CA[i]; CLb[i] = CB[i]; }
  __syncthreads();
  int lane = tid & 63;
  int n0 = (blockIdx.x * 4 + (tid >> 6)) * 16;   // 16 nodes per wave
  if (n0 >= Nd) return;
  int ne = min(n0 + 16, Nd);
  float p0 = 0.f, p1 = 0.f;                       // pool partials, cols lane & 64+lane
  int curb = batch[n0];
  for (int n = n0; n < ne; ++n) {
    int bb = batch[n];
    if (bb != curb) {
      atomicAdd(&xcat[curb * 512 + colofs + lane], p0);
      atomicAdd(&xcat[curb * 512 + colofs + 64 + lane], p1);
      p0 = 0.f; p1 = 0.f; curb = bb;
    }
    agg_list<KA>(RS, SE, sbA + n, srcA, xA, CLa, lsA, ldA[n], lane, p0, p1);
    agg_list<KB>(RS, SE, sbB + n, srcB, xB, CLb, lsB, ldB[n], lane, p0, p1);
  }
  atomicAdd(&xcat[curb * 512 + colofs + lane], p0);
  atomicAdd(&xcat[curb * 512 + colofs + 64 + lane], p1);
}

// ---------------------------------------------------------------------------
__device__ __forceinline__ int lowb(const int* a, int n, int v) {
  int lo = 0, hi = n;
  while (lo < hi) { int mid = (lo + hi) >> 1; if (a[mid] < v) lo = mid + 1; else hi = mid; }
  return lo;
}

__global__ __launch_bounds__(128) void finalize_kernel(
    const int* __restrict__ bt, const int* __restrict__ brv, const int* __restrict__ br,
    const float* __restrict__ xp,
    const float* __restrict__ fc1W, const float* __restrict__ fc1b,
    const float* __restrict__ fc2W, const float* __restrict__ fc2b,
    const float* __restrict__ b_rv2t, const float* __restrict__ b_r2t,
    const float* __restrict__ b_t2rv, const float* __restrict__ b_r2rv,
    const float* __restrict__ b_rv2r, const float* __restrict__ b_t2r,
    float* __restrict__ xcat)
{
  int b = blockIdx.x, tid = threadIdx.x;
  __shared__ float xps[64];
  __shared__ float p1s[128];
  __shared__ int cnts[3];
  if (tid < 64) xps[tid] = xp[b * 64 + tid];
  if (tid < 3) {
    const int* ba = (tid == 0) ? bt : (tid == 1 ? brv : br);
    int N = (tid == 0) ? kNT : (tid == 1 ? kNRV : kNR);
    cnts[tid] = lowb(ba, N, b + 1) - lowb(ba, N, b);
  }
  __syncthreads();
  float a = fc1b[tid];
  for (int k = 0; k < 64; ++k) a += xps[k] * fc1W[k * 128 + tid];
  p1s[tid] = fmaxf(a, 0.f);
  __syncthreads();
  float a2 = fc2b[tid];
  for (int k = 0; k < 128; ++k) a2 += p1s[k] * fc2W[k * 128 + tid];
  xcat[b * 512 + 384 + tid] = fmaxf(a2, 0.f);
  for (int t3 = 0; t3 < 3; ++t3) {
    int c = t3 * 128 + tid;
    float cnt = (float)max(cnts[t3], 1);
    const float* bb1 = (t3 == 0) ? b_rv2t : (t3 == 1 ? b_t2rv : b_rv2r);
    const float* bb2 = (t3 == 0) ? b_r2t  : (t3 == 1 ? b_r2rv : b_t2r);
    xcat[b * 512 + c] = xcat[b * 512 + c] / cnt + bb1[tid] + bb2[tid];
  }
}

// ---------------------------------------------------------------------------
__global__ __launch_bounds__(256) void out_kernel(
    const float* __restrict__ xcat, const float* __restrict__ outW,
    const float* __restrict__ outb, float* __restrict__ out)
{
  int g = blockIdx.x * 256 + threadIdx.x;   // 64*512
  int r = g >> 9, c = g & 511;
  const float* xr = xcat + r * 512;
  float acc = outb[c];
  for (int k = 0; k < 512; ++k) acc += xr[k] * outW[k * 512 + c];
  out[g] = acc;
}

// ---------------------------------------------------------------------------
extern "C" void kernel_launch(void* const* d_in, const int* in_sizes, int n_in,
                              void* d_out, int out_size, void* d_ws, size_t ws_size,
                              hipStream_t stream) {
  const float* x_tile   = (const float*)d_in[0];
  const float* x_rv     = (const float*)d_in[1];
  const float* x_road   = (const float*)d_in[2];
  const float* x_player = (const float*)d_in[3];
  const float* enc_t_W  = (const float*)d_in[4];
  const float* enc_t_b  = (const float*)d_in[5];
  const float* enc_rv_W = (const float*)d_in[6];
  const float* enc_rv_b = (const float*)d_in[7];
  const float* enc_r_W  = (const float*)d_in[8];
  const float* enc_r_b  = (const float*)d_in[9];
  // 6 GATs: W, a_s, a_d, b at 10 + 4*et
  const float* W[6]; const float* As[6]; const float* Ad[6]; const float* Bb[6];
  for (int et = 0; et < 6; ++et) {
    W[et]  = (const float*)d_in[10 + 4 * et];
    As[et] = (const float*)d_in[11 + 4 * et];
    Ad[et] = (const float*)d_in[12 + 4 * et];
    Bb[et] = (const float*)d_in[13 + 4 * et];
  }
  const float* fc1W = (const float*)d_in[34];
  const float* fc1b = (const float*)d_in[35];
  const float* fc2W = (const float*)d_in[36];
  const float* fc2b = (const float*)d_in[37];
  const float* outW = (const float*)d_in[38];
  const float* outb = (const float*)d_in[39];
  const int* esrc[6]; const int* edst[6];
  for (int et = 0; et < 6; ++et) {
    esrc[et] = (const int*)d_in[40 + 2 * et];
    edst[et] = (const int*)d_in[41 + 2 * et];
  }
  const int* batch_t  = (const int*)d_in[52];
  const int* batch_rv = (const int*)d_in[53];
  const int* batch_r  = (const int*)d_in[54];

  int*   wsI = (int*)d_ws;
  float* wsF = (float*)d_ws;
  int* CC = wsI + OFF_CC;
  int* CU = wsI + OFF_CU;
  int* RS = wsI + OFF_RS;
  int* SE = wsI + OFF_SE;
  int* BS = wsI + OFF_BSUM;
  int* BO = wsI + OFF_BOFF;
  float* Cws  = wsF + OFF_C;
  float* vsw  = wsF + OFF_VS;
  float* vdw  = wsF + OFF_VD;
  float* lsb  = wsF + OFF_LS;
  float* ldb  = wsF + OFF_LD;
  float* xcat = wsF + OFF_XCAT;
  float* out  = (float*)d_out;

  // ls per-et (src-indexed) and ld per-et (dst-indexed) sub-arrays
  float* ls[6] = {lsb + 0, lsb + 200000, lsb + 300000, lsb + 600000, lsb + 800000, lsb + 900000};
  float* ld[6] = {ldb + 0, ldb + 100000, ldb + 300000, ldb + 500000, ldb + 800000, ldb + 1100000};
  const int SB[6] = {0, 100000, 300000, 500000, 800000, 1100000};  // dst segment bases

  zero_kernel<<<(kTOTE + 255) / 256, 256, 0, stream>>>(CC, xcat, RS);

  precompute_kernel<<<6, 256, 0, stream>>>(
      enc_t_W, enc_t_b, enc_rv_W, enc_rv_b, enc_r_W, enc_r_b,
      W[0], As[0], Ad[0], W[1], As[1], Ad[1], W[2], As[2], Ad[2],
      W[3], As[3], Ad[3], W[4], As[4], Ad[4], W[5], As[5], Ad[5],
      Cws, vsw, vdw);

  // logits: tile src roles {t2rv=1, t2r=4}, dst roles {rv2t=0, r2t=5}
  logit_kernel<8><<<(kNT + 255) / 256, 256, 0, stream>>>(
      x_tile, kNT, vsw + 1 * 20, vsw + 4 * 20, vdw + 0 * 20, vdw + 5 * 20,
      ls[1], ls[4], ld[0], ld[5]);
  // rv src {rv2t=0, rv2r=3}, dst {t2rv=1, r2rv=2}
  logit_kernel<13><<<(kNRV + 255) / 256, 256, 0, stream>>>(
      x_rv, kNRV, vsw + 0 * 20, vsw + 3 * 20, vdw + 1 * 20, vdw + 2 * 20,
      ls[0], ls[3], ld[1], ld[2]);
  // road src {r2rv=2, r2t=5}, dst {rv2r=3, t2r=4}
  logit_kernel<4><<<(kNR + 255) / 256, 256, 0, stream>>>(
      x_road, kNR, vsw + 2 * 20, vsw + 5 * 20, vdw + 3 * 20, vdw + 4 * 20,
      ls[2], ls[5], ld[3], ld[4]);

  // CSR build (concatenated over all 6 edge types)
  hist_kernel<<<(kTOTE + 255) / 256, 256, 0, stream>>>(
      edst[0], edst[1], edst[2], edst[3], edst[4], edst[5], CC);
  scan1_kernel<<<kNB1, 256, 0, stream>>>(CC, BS);
  scan2_kernel<<<1, 256, 0, stream>>>(BS, BO);
  scan3_kernel<<<kNB1, 256, 0, stream>>>(CC, BO, RS);
  scatter_kernel<<<(kTOTE + 255) / 256, 256, 0, stream>>>(
      edst[0], edst[1], edst[2], edst[3], edst[4], edst[5], RS, CU, SE);

  // aggregation + fused mean-pool accumulation
  // o_t = gat(rv2t: K=13) + gat(r2t: K=4)
  agg_kernel<13, 4><<<(kNT + 63) / 64, 256, 0, stream>>>(
      RS, SE,
      SB[0], esrc[0], x_rv,   Cws + 0 * 2176, ls[0], ld[0],
      SB[5], esrc[5], x_road, Cws + 5 * 2176, ls[5], ld[5],
      batch_t, xcat, 0, kNT);
  // o_rv = gat(t2rv: K=8) + gat(r2rv: K=4)
  agg_kernel<8, 4><<<(kNRV + 63) / 64, 256, 0, stream>>>(
      RS, SE,
      SB[1], esrc[1], x_tile, Cws + 1 * 2176, ls[1], ld[1],
      SB[2], esrc[2], x_road, Cws + 2 * 2176, ls[2], ld[2],
      batch_rv, xcat, 128, kNRV);
  // o_r = gat(rv2r: K=13) + gat(t2r: K=8)
  agg_kernel<13, 8><<<(kNR + 63) / 64, 256, 0, stream>>>(
      RS, SE,
      SB[3], esrc[3], x_rv,   Cws + 3 * 2176, ls[3], ld[3],
      SB[4], esrc[4], x_tile, Cws + 4 * 2176, ls[4], ld[4],
      batch_r, xcat, 256, kNR);

  finalize_kernel<<<64, 128, 0, stream>>>(
      batch_t, batch_rv, batch_r, x_player,
      fc1W, fc1b, fc2W, fc2b,
      Bb[0], Bb[5], Bb[1], Bb[2], Bb[3], Bb[4], xcat);

  out_kernel<<<128, 256, 0, stream>>>(xcat, outW, outb, out);

  (void)in_sizes; (void)n_in; (void)out_size; (void)ws_size;
}

// Round 2
// 617.854 us; speedup vs baseline: 2.0371x; 2.0371x over previous
//
#include <hip/hip_runtime.h>

// ---------------------------------------------------------------------------
// GNNQNetwork hetero-GAT, MI355X fp32.
//
// Round-2 restructure: aggregation accumulates K-dim weighted source-feature
// sums per dst node (Sum w*x / Sum w), reduced per-batch into P[6][64][16].
// The [K x 128] transform C and cb bias are applied once per (batch, edge
// type) in finalize — no 128-wide per-edge or per-node work at all.
// ---------------------------------------------------------------------------

constexpr int kNT   = 100000;
constexpr int kNRV  = 200000;
constexpr int kNR   = 300000;
constexpr int kE    = 400000;
constexpr int kTOTD = 1200000;   // concatenated dst-count array (all 6 ets)
constexpr int kTOTE = 2400000;   // 6*E
constexpr int kNB1  = 1172;      // ceil(kTOTD/1024)

constexpr int kBT  = (kNT  + 255) / 256;   // 391
constexpr int kBRV = (kNRV + 255) / 256;   // 782
constexpr int kBR  = (kNR  + 255) / 256;   // 1172

// workspace offsets, in 4-byte units
constexpr long long OFF_CC   = 0;        // [1200000] int counts
constexpr long long OFF_CU   = 1200000;  // [1200000] int cursors
constexpr long long OFF_RS   = 2400000;  // [1200001] int row starts
constexpr long long OFF_SE   = 3600004;  // [2400000] int sorted SRC ids
constexpr long long OFF_BSUM = 6000004;  // [1172]
constexpr long long OFF_BOFF = 6001184;  // [1280]
constexpr long long OFF_C    = 6002464;  // [6*2176] float C rows + cb@2048
constexpr long long OFF_VS   = 6015520;  // [6*20]
constexpr long long OFF_VD   = 6015640;  // [6*20]
constexpr long long OFF_LS   = 6015760;  // [1200000] float src logits
constexpr long long OFF_LD   = 7215760;  // [1200000] float dst logits
constexpr long long OFF_P    = 8415760;  // [6*64*16] float batch partials
constexpr long long OFF_XCAT = 8421904;  // [64*512]
// total ~33.8 MB

// ---------------------------------------------------------------------------
__global__ __launch_bounds__(256) void zero_kernel(int* cc, float* P, int* rs) {
  int i = blockIdx.x * 256 + threadIdx.x;
  if (i < kTOTE) cc[i] = 0;                 // zeroes CC and CU (contiguous)
  if (i < 6 * 64 * 16) P[i] = 0.f;
  if (i == 0) rs[kTOTD] = kTOTE;            // scan sentinel
}

// ---------------------------------------------------------------------------
__global__ __launch_bounds__(256) void precompute_kernel(
    const float* encW_t, const float* encb_t,
    const float* encW_rv, const float* encb_rv,
    const float* encW_r, const float* encb_r,
    const float* W0, const float* as0, const float* ad0,
    const float* W1, const float* as1, const float* ad1,
    const float* W2, const float* as2, const float* ad2,
    const float* W3, const float* as3, const float* ad3,
    const float* W4, const float* as4, const float* ad4,
    const float* W5, const float* as5, const float* ad5,
    float* Cws, float* vsw, float* vdw)
{
  const float* encW[3] = {encW_t, encW_rv, encW_r};
  const float* encb[3] = {encb_t, encb_rv, encb_r};
  const int    Ks[3]   = {8, 13, 4};
  const float* Wv[6]  = {W0, W1, W2, W3, W4, W5};
  const float* asv[6] = {as0, as1, as2, as3, as4, as5};
  const float* adv[6] = {ad0, ad1, ad2, ad3, ad4, ad5};
  const int srcT[6] = {1, 0, 2, 1, 0, 2};   // et -> src type {t=0,rv=1,r=2}
  const int dstT[6] = {0, 1, 1, 2, 2, 0};

  __shared__ float Cl[2176];
  __shared__ float wv[128];

  int et = blockIdx.x;
  int tid = threadIdx.x;
  int st = srcT[et], dt = dstT[et];
  const float* eW = encW[st];
  const float* eB = encb[st];
  int K = Ks[st];
  const float* W = Wv[et];
  const float* a_s = asv[et];
  const float* a_d = adv[et];
  float* Cslot = Cws + et * 2176;

  for (int idx = tid; idx < (K + 1) * 128; idx += 256) {
    int r = idx >> 7, j = idx & 127;
    const float* row = (r < K) ? (eW + r * 128) : eB;
    float acc = 0.f;
    for (int m = 0; m < 128; ++m) acc += row[m] * W[m * 128 + j];
    int o = (r < K) ? (r * 128 + j) : (2048 + j);
    Cl[o] = acc;
    Cslot[o] = acc;
  }
  if (tid < 128) {
    float acc = 0.f;
    for (int j = 0; j < 128; ++j) acc += W[tid * 128 + j] * a_d[j];
    wv[tid] = acc;
  }
  __syncthreads();
  if (tid <= K) {
    const float* row = (tid < K) ? (Cl + tid * 128) : (Cl + 2048);
    float acc = 0.f;
    for (int j = 0; j < 128; ++j) acc += row[j] * a_s[j];
    vsw[et * 20 + (tid < K ? tid : 16)] = acc;
  }
  int KD = Ks[dt];
  if (tid >= 32 && tid <= 32 + KD) {
    int k = tid - 32;
    const float* row = (k < KD) ? (encW[dt] + k * 128) : encb[dt];
    float acc = 0.f;
    for (int m = 0; m < 128; ++m) acc += row[m] * wv[m];
    vdw[et * 20 + (k < KD ? k : 16)] = acc;
  }
}

// ---------------------------------------------------------------------------
template <int K>
__global__ __launch_bounds__(256) void logit_kernel(
    const float* __restrict__ x, int N,
    const float* __restrict__ vsA, const float* __restrict__ vsB,
    const float* __restrict__ vdA, const float* __restrict__ vdB,
    float* __restrict__ lsA, float* __restrict__ lsB,
    float* __restrict__ ldA, float* __restrict__ ldB)
{
  int n = blockIdx.x * 256 + threadIdx.x;
  if (n >= N) return;
  const float* xr = x + n * K;
  float a0 = 0.f, a1 = 0.f, a2 = 0.f, a3 = 0.f;
#pragma unroll
  for (int k = 0; k < K; ++k) {
    float xv = xr[k];
    a0 += xv * vsA[k]; a1 += xv * vsB[k];
    a2 += xv * vdA[k]; a3 += xv * vdB[k];
  }
  lsA[n] = a0 + vsA[16]; lsB[n] = a1 + vsB[16];
  ldA[n] = a2 + vdA[16]; ldB[n] = a3 + vdB[16];
}

// ---------------------------------------------------------------------------
__global__ __launch_bounds__(256) void hist_kernel(
    const int* d0, const int* d1, const int* d2,
    const int* d3, const int* d4, const int* d5, int* CC)
{
  int i = blockIdx.x * 256 + threadIdx.x;
  if (i >= kTOTE) return;
  int et = i / kE;
  int e = i - et * kE;
  const int* dp; int sb;
  switch (et) {
    case 0: dp = d0; sb = 0;       break;
    case 1: dp = d1; sb = 100000;  break;
    case 2: dp = d2; sb = 300000;  break;
    case 3: dp = d3; sb = 500000;  break;
    case 4: dp = d4; sb = 800000;  break;
    default: dp = d5; sb = 1100000; break;
  }
  atomicAdd(&CC[sb + dp[e]], 1);
}

// ---------------------------------------------------------------------------
__global__ __launch_bounds__(256) void scan1_kernel(const int* __restrict__ CC, int* bsum) {
  __shared__ int sd[256];
  int b = blockIdx.x, t = threadIdx.x;
  int i0 = b * 1024 + t * 4;
  int s = 0;
  if (i0 + 3 < kTOTD) {
    int4 v = *(const int4*)(CC + i0);
    s = v.x + v.y + v.z + v.w;
  } else {
    for (int j = 0; j < 4; ++j) if (i0 + j < kTOTD) s += CC[i0 + j];
  }
  sd[t] = s; __syncthreads();
  for (int o = 128; o > 0; o >>= 1) { if (t < o) sd[t] += sd[t + o]; __syncthreads(); }
  if (t == 0) bsum[b] = sd[0];
}

__global__ __launch_bounds__(256) void scan2_kernel(const int* __restrict__ bsum, int* boff) {
  __shared__ int sc[256];
  int t = threadIdx.x;
  int g[5], c[5], run = 0;
  for (int j = 0; j < 5; ++j) {
    int idx = t * 5 + j;
    g[j] = (idx < kNB1) ? bsum[idx] : 0;
    run += g[j]; c[j] = run;
  }
  sc[t] = run; __syncthreads();
  for (int o = 1; o < 256; o <<= 1) {
    int v = (t >= o) ? sc[t - o] : 0;
    __syncthreads();
    sc[t] += v;
    __syncthreads();
  }
  int ex = sc[t] - run;
  for (int j = 0; j < 5; ++j) {
    int idx = t * 5 + j;
    if (idx < kNB1) boff[idx] = ex + c[j] - g[j];
  }
}

__global__ __launch_bounds__(256) void scan3_kernel(const int* __restrict__ CC,
                                                    const int* __restrict__ boff,
                                                    int* __restrict__ RS) {
  __shared__ int sc[256];
  int b = blockIdx.x, t = threadIdx.x;
  int i0 = b * 1024 + t * 4;
  int v[4];
  if (i0 + 3 < kTOTD) {
    int4 q = *(const int4*)(CC + i0);
    v[0] = q.x; v[1] = q.y; v[2] = q.z; v[3] = q.w;
  } else {
    for (int j = 0; j < 4; ++j) v[j] = (i0 + j < kTOTD) ? CC[i0 + j] : 0;
  }
  int run = 0, inc[4];
  for (int j = 0; j < 4; ++j) { run += v[j]; inc[j] = run; }
  sc[t] = run; __syncthreads();
  for (int o = 1; o < 256; o <<= 1) {
    int x = (t >= o) ? sc[t - o] : 0;
    __syncthreads();
    sc[t] += x;
    __syncthreads();
  }
  int ex = boff[b] + sc[t] - run;
  for (int j = 0; j < 4; ++j)
    if (i0 + j < kTOTD) RS[i0 + j] = ex + inc[j] - v[j];
}

// ---------------------------------------------------------------------------
// Writes SRC node id (not edge id) into the CSR value array: removes one
// dependent gather from the aggregation per-edge load chain.
__global__ __launch_bounds__(256) void scatter_kernel(
    const int* d0, const int* d1, const int* d2,
    const int* d3, const int* d4, const int* d5,
    const int* s0, const int* s1, const int* s2,
    const int* s3, const int* s4, const int* s5,
    const int* __restrict__ RS, int* CU, int* SE)
{
  int i = blockIdx.x * 256 + threadIdx.x;
  if (i >= kTOTE) return;
  int et = i / kE;
  int e = i - et * kE;
  const int* dp; const int* sp; int sb;
  switch (et) {
    case 0: dp = d0; sp = s0; sb = 0;       break;
    case 1: dp = d1; sp = s1; sb = 100000;  break;
    case 2: dp = d2; sp = s2; sb = 300000;  break;
    case 3: dp = d3; sp = s3; sb = 500000;  break;
    case 4: dp = d4; sp = s4; sb = 800000;  break;
    default: dp = d5; sp = s5; sb = 1100000; break;
  }
  int d = dp[e];
  int p = RS[sb + d] + atomicAdd(&CU[sb + d], 1);
  SE[p] = sp[e];
}

// ---------------------------------------------------------------------------
// Per-node GAT: K-dim weighted source sum, normalization deferred.
template <int K>
__device__ __forceinline__ float node_gat(
    const int* __restrict__ RS, const int* __restrict__ SEs, int base,
    const float* __restrict__ x, const float* __restrict__ ls, float ldn,
    float* acc)
{
#pragma unroll
  for (int k = 0; k < K; ++k) acc[k] = 0.f;
  int s0 = RS[base], s1 = RS[base + 1];
  if (s0 >= s1) return 0.f;
  float denom = 0.f;
  for (int i = s0; i < s1; ++i) {
    int s = SEs[i];
    float t = ls[s] + ldn;
    t = t > 0.f ? t : 0.2f * t;
    float w = __expf(t);
    denom += w;
    const float* xr = x + s * K;
#pragma unroll
    for (int k = 0; k < K; ++k) acc[k] += w * xr[k];
  }
  float inv = 1.f / fmaxf(denom, 1e-16f);
#pragma unroll
  for (int k = 0; k < K; ++k) acc[k] *= inv;
  return 1.f;
}

template <int K>
__device__ __forceinline__ void flushP(float* acc, float cnt, int bb, int lane,
                                       float* __restrict__ Pet)
{
  int first = __builtin_amdgcn_readfirstlane(bb);
  bool uni = __all(bb == first);
  if (uni) {
#pragma unroll
    for (int k = 0; k < K; ++k) {
      float v = acc[k];
      v += __shfl_xor(v, 32, 64); v += __shfl_xor(v, 16, 64);
      v += __shfl_xor(v, 8, 64);  v += __shfl_xor(v, 4, 64);
      v += __shfl_xor(v, 2, 64);  v += __shfl_xor(v, 1, 64);
      acc[k] = v;
    }
    float c = cnt;
    c += __shfl_xor(c, 32, 64); c += __shfl_xor(c, 16, 64);
    c += __shfl_xor(c, 8, 64);  c += __shfl_xor(c, 4, 64);
    c += __shfl_xor(c, 2, 64);  c += __shfl_xor(c, 1, 64);
    if (lane == 0) {
      float* p = Pet + first * 16;
#pragma unroll
      for (int k = 0; k < K; ++k) atomicAdd(p + k, acc[k]);
      atomicAdd(p + 15, c);
    }
  } else if (cnt > 0.f) {
    float* p = Pet + bb * 16;
#pragma unroll
    for (int k = 0; k < K; ++k) atomicAdd(p + k, acc[k]);
    atomicAdd(p + 15, 1.f);
  }
}

template <int KA, int KB>
__device__ __forceinline__ void agg_type(
    const int* __restrict__ RS, const int* __restrict__ SEs,
    int sbA, const float* __restrict__ xA, const float* __restrict__ lsA,
    const float* __restrict__ ldA, float* __restrict__ PA,
    int sbB, const float* __restrict__ xB, const float* __restrict__ lsB,
    const float* __restrict__ ldB, float* __restrict__ PB,
    const int* __restrict__ batch, int Nd, int nblk)
{
  int n = nblk * 256 + (int)threadIdx.x;
  int lane = threadIdx.x & 63;
  bool valid = n < Nd;
  int nc = valid ? n : (Nd - 1);
  int bb = batch[nc];
  {
    float acc[KA];
    float cnt = 0.f;
    if (valid) cnt = node_gat<KA>(RS, SEs, sbA + n, xA, lsA, ldA[n], acc);
    else {
#pragma unroll
      for (int k = 0; k < KA; ++k) acc[k] = 0.f;
    }
    flushP<KA>(acc, cnt, bb, lane, PA);
  }
  {
    float acc[KB];
    float cnt = 0.f;
    if (valid) cnt = node_gat<KB>(RS, SEs, sbB + n, xB, lsB, ldB[n], acc);
    else {
#pragma unroll
      for (int k = 0; k < KB; ++k) acc[k] = 0.f;
    }
    flushP<KB>(acc, cnt, bb, lane, PB);
  }
}

__global__ __launch_bounds__(256) void agg_kernel(
    const int* __restrict__ RS, const int* __restrict__ SEs,
    const float* __restrict__ x_tile, const float* __restrict__ x_rv,
    const float* __restrict__ x_road,
    const float* __restrict__ ls0, const float* __restrict__ ls1,
    const float* __restrict__ ls2, const float* __restrict__ ls3,
    const float* __restrict__ ls4, const float* __restrict__ ls5,
    const float* __restrict__ ld0, const float* __restrict__ ld1,
    const float* __restrict__ ld2, const float* __restrict__ ld3,
    const float* __restrict__ ld4, const float* __restrict__ ld5,
    const int* __restrict__ batch_t, const int* __restrict__ batch_rv,
    const int* __restrict__ batch_r, float* __restrict__ P)
{
  int blk = blockIdx.x;
  if (blk < kBT) {
    // tiles: ets rv2t(0, K=13, src=rv) + r2t(5, K=4, src=road)
    agg_type<13, 4>(RS, SEs,
                    0,       x_rv,   ls0, ld0, P + 0 * 64 * 16,
                    1100000, x_road, ls5, ld5, P + 5 * 64 * 16,
                    batch_t, kNT, blk);
  } else if (blk < kBT + kBRV) {
    // road_vertices: t2rv(1, K=8, src=tile) + r2rv(2, K=4, src=road)
    agg_type<8, 4>(RS, SEs,
                   100000, x_tile, ls1, ld1, P + 1 * 64 * 16,
                   300000, x_road, ls2, ld2, P + 2 * 64 * 16,
                   batch_rv, kNRV, blk - kBT);
  } else {
    // roads: rv2r(3, K=13, src=rv) + t2r(4, K=8, src=tile)
    agg_type<13, 8>(RS, SEs,
                    500000, x_rv,   ls3, ld3, P + 3 * 64 * 16,
                    800000, x_tile, ls4, ld4, P + 4 * 64 * 16,
                    batch_r, kNR, blk - kBT - kBRV);
  }
}

// ---------------------------------------------------------------------------
__device__ __forceinline__ int lowb(const int* a, int n, int v) {
  int lo = 0, hi = n;
  while (lo < hi) { int mid = (lo + hi) >> 1; if (a[mid] < v) lo = mid + 1; else hi = mid; }
  return lo;
}

__global__ __launch_bounds__(128) void finalize_kernel(
    const int* __restrict__ bt, const int* __restrict__ brv, const int* __restrict__ br,
    const float* __restrict__ xp,
    const float* __restrict__ fc1W, const float* __restrict__ fc1b,
    const float* __restrict__ fc2W, const float* __restrict__ fc2b,
    const float* __restrict__ b_rv2t, const float* __restrict__ b_r2t,
    const float* __restrict__ b_t2rv, const float* __restrict__ b_r2rv,
    const float* __restrict__ b_rv2r, const float* __restrict__ b_t2r,
    const float* __restrict__ Cws, const float* __restrict__ P,
    float* __restrict__ xcat)
{
  int b = blockIdx.x, tid = threadIdx.x;
  __shared__ float xps[64];
  __shared__ float p1s[128];
  __shared__ int cnts[3];
  if (tid < 64) xps[tid] = xp[b * 64 + tid];
  if (tid < 3) {
    const int* ba = (tid == 0) ? bt : (tid == 1 ? brv : br);
    int N = (tid == 0) ? kNT : (tid == 1 ? kNRV : kNR);
    cnts[tid] = lowb(ba, N, b + 1) - lowb(ba, N, b);
  }
  __syncthreads();
  // player MLP
  float a = fc1b[tid];
  for (int k = 0; k < 64; ++k) a += xps[k] * fc1W[k * 128 + tid];
  p1s[tid] = fmaxf(a, 0.f);
  __syncthreads();
  float a2 = fc2b[tid];
  for (int k = 0; k < 128; ++k) a2 += p1s[k] * fc2W[k * 128 + tid];
  xcat[b * 512 + 384 + tid] = fmaxf(a2, 0.f);
  // pooled GAT columns: (P@C + cntE*cb)/cnt + biases
  const int etA[3] = {0, 1, 3}, etB[3] = {5, 2, 4};
  const int KAv[3] = {13, 8, 13}, KBv[3] = {4, 4, 8};
  for (int t3 = 0; t3 < 3; ++t3) {
    int eA = etA[t3], eB = etB[t3];
    const float* CA = Cws + eA * 2176;
    const float* CB = Cws + eB * 2176;
    const float* pA = P + (eA * 64 + b) * 16;
    const float* pB = P + (eB * 64 + b) * 16;
    float v = pA[15] * CA[2048 + tid] + pB[15] * CB[2048 + tid];
    for (int k = 0; k < KAv[t3]; ++k) v += pA[k] * CA[k * 128 + tid];
    for (int k = 0; k < KBv[t3]; ++k) v += pB[k] * CB[k * 128 + tid];
    float cnt = (float)max(cnts[t3], 1);
    const float* bb1 = (t3 == 0) ? b_rv2t : (t3 == 1 ? b_t2rv : b_rv2r);
    const float* bb2 = (t3 == 0) ? b_r2t  : (t3 == 1 ? b_r2rv : b_t2r);
    xcat[b * 512 + t3 * 128 + tid] = v / cnt + bb1[tid] + bb2[tid];
  }
}

// ---------------------------------------------------------------------------
__global__ __launch_bounds__(256) void out_kernel(
    const float* __restrict__ xcat, const float* __restrict__ outW,
    const float* __restrict__ outb, float* __restrict__ out)
{
  int g = blockIdx.x * 256 + threadIdx.x;   // 64*512
  int r = g >> 9, c = g & 511;
  const float* xr = xcat + r * 512;
  float acc = outb[c];
  for (int k = 0; k < 512; ++k) acc += xr[k] * outW[k * 512 + c];
  out[g] = acc;
}

// ---------------------------------------------------------------------------
extern "C" void kernel_launch(void* const* d_in, const int* in_sizes, int n_in,
                              void* d_out, int out_size, void* d_ws, size_t ws_size,
                              hipStream_t stream) {
  const float* x_tile   = (const float*)d_in[0];
  const float* x_rv     = (const float*)d_in[1];
  const float* x_road   = (const float*)d_in[2];
  const float* x_player = (const float*)d_in[3];
  const float* enc_t_W  = (const float*)d_in[4];
  const float* enc_t_b  = (const float*)d_in[5];
  const float* enc_rv_W = (const float*)d_in[6];
  const float* enc_rv_b = (const float*)d_in[7];
  const float* enc_r_W  = (const float*)d_in[8];
  const float* enc_r_b  = (const float*)d_in[9];
  const float* W[6]; const float* As[6]; const float* Ad[6]; const float* Bb[6];
  for (int et = 0; et < 6; ++et) {
    W[et]  = (const float*)d_in[10 + 4 * et];
    As[et] = (const float*)d_in[11 + 4 * et];
    Ad[et] = (const float*)d_in[12 + 4 * et];
    Bb[et] = (const float*)d_in[13 + 4 * et];
  }
  const float* fc1W = (const float*)d_in[34];
  const float* fc1b = (const float*)d_in[35];
  const float* fc2W = (const float*)d_in[36];
  const float* fc2b = (const float*)d_in[37];
  const float* outW = (const float*)d_in[38];
  const float* outb = (const float*)d_in[39];
  const int* esrc[6]; const int* edst[6];
  for (int et = 0; et < 6; ++et) {
    esrc[et] = (const int*)d_in[40 + 2 * et];
    edst[et] = (const int*)d_in[41 + 2 * et];
  }
  const int* batch_t  = (const int*)d_in[52];
  const int* batch_rv = (const int*)d_in[53];
  const int* batch_r  = (const int*)d_in[54];

  int*   wsI = (int*)d_ws;
  float* wsF = (float*)d_ws;
  int* CC = wsI + OFF_CC;
  int* CU = wsI + OFF_CU;
  int* RS = wsI + OFF_RS;
  int* SE = wsI + OFF_SE;
  int* BS = wsI + OFF_BSUM;
  int* BO = wsI + OFF_BOFF;
  float* Cws  = wsF + OFF_C;
  float* vsw  = wsF + OFF_VS;
  float* vdw  = wsF + OFF_VD;
  float* lsb  = wsF + OFF_LS;
  float* ldb  = wsF + OFF_LD;
  float* P    = wsF + OFF_P;
  float* xcat = wsF + OFF_XCAT;
  float* out  = (float*)d_out;

  float* ls[6] = {lsb + 0, lsb + 200000, lsb + 300000, lsb + 600000, lsb + 800000, lsb + 900000};
  float* ld[6] = {ldb + 0, ldb + 100000, ldb + 300000, ldb + 500000, ldb + 800000, ldb + 1100000};

  zero_kernel<<<(kTOTE + 255) / 256, 256, 0, stream>>>(CC, P, RS);

  precompute_kernel<<<6, 256, 0, stream>>>(
      enc_t_W, enc_t_b, enc_rv_W, enc_rv_b, enc_r_W, enc_r_b,
      W[0], As[0], Ad[0], W[1], As[1], Ad[1], W[2], As[2], Ad[2],
      W[3], As[3], Ad[3], W[4], As[4], Ad[4], W[5], As[5], Ad[5],
      Cws, vsw, vdw);

  logit_kernel<8><<<(kNT + 255) / 256, 256, 0, stream>>>(
      x_tile, kNT, vsw + 1 * 20, vsw + 4 * 20, vdw + 0 * 20, vdw + 5 * 20,
      ls[1], ls[4], ld[0], ld[5]);
  logit_kernel<13><<<(kNRV + 255) / 256, 256, 0, stream>>>(
      x_rv, kNRV, vsw + 0 * 20, vsw + 3 * 20, vdw + 1 * 20, vdw + 2 * 20,
      ls[0], ls[3], ld[1], ld[2]);
  logit_kernel<4><<<(kNR + 255) / 256, 256, 0, stream>>>(
      x_road, kNR, vsw + 2 * 20, vsw + 5 * 20, vdw + 3 * 20, vdw + 4 * 20,
      ls[2], ls[5], ld[3], ld[4]);

  hist_kernel<<<(kTOTE + 255) / 256, 256, 0, stream>>>(
      edst[0], edst[1], edst[2], edst[3], edst[4], edst[5], CC);
  scan1_kernel<<<kNB1, 256, 0, stream>>>(CC, BS);
  scan2_kernel<<<1, 256, 0, stream>>>(BS, BO);
  scan3_kernel<<<kNB1, 256, 0, stream>>>(CC, BO, RS);
  scatter_kernel<<<(kTOTE + 255) / 256, 256, 0, stream>>>(
      edst[0], edst[1], edst[2], edst[3], edst[4], edst[5],
      esrc[0], esrc[1], esrc[2], esrc[3], esrc[4], esrc[5], RS, CU, SE);

  agg_kernel<<<kBT + kBRV + kBR, 256, 0, stream>>>(
      RS, SE, x_tile, x_rv, x_road,
      ls[0], ls[1], ls[2], ls[3], ls[4], ls[5],
      ld[0], ld[1], ld[2], ld[3], ld[4], ld[5],
      batch_t, batch_rv, batch_r, P);

  finalize_kernel<<<64, 128, 0, stream>>>(
      batch_t, batch_rv, batch_r, x_player,
      fc1W, fc1b, fc2W, fc2b,
      Bb[0], Bb[5], Bb[1], Bb[2], Bb[3], Bb[4],
      Cws, P, xcat);

  out_kernel<<<128, 256, 0, stream>>>(xcat, outW, outb, out);

  (void)in_sizes; (void)n_in; (void)out_size; (void)ws_size;
}